// Round 10
// baseline (82.517 us; speedup 1.0000x reference)
//
#include <hip/hip_runtime.h>

#define DHW  8192
#define COFF 108

typedef __attribute__((ext_vector_type(8))) short bf16x8;
typedef __attribute__((ext_vector_type(4))) float f32x4;
typedef __bf16 bfv2 __attribute__((ext_vector_type(2)));

__device__ inline unsigned short f2bf(float f) {
    unsigned u = __float_as_uint(f);
    u += 0x7fffu + ((u >> 16) & 1u);     // RNE
    return (unsigned short)(u >> 16);
}
__device__ inline float bf2f(unsigned short h) {
    return __uint_as_float(((unsigned)h) << 16);
}

// dot2: c += a.lo*b.lo + a.hi*b.hi  (bf16 pairs packed in dwords)
__device__ inline float dot2bf(unsigned a, unsigned b, float c) {
#if defined(__has_builtin) && __has_builtin(__builtin_amdgcn_fdot2_f32_bf16)
    return __builtin_amdgcn_fdot2_f32_bf16(__builtin_bit_cast(bfv2, a),
                                           __builtin_bit_cast(bfv2, b), c, false);
#else
    c += __uint_as_float(a << 16) * __uint_as_float(b << 16);
    c += __uint_as_float(a & 0xffff0000u) * __uint_as_float(b & 0xffff0000u);
    return c;
#endif
}

// ---------------- kernel A: xt transpose + weight packing -------------------
__global__ __launch_bounds__(256) void k_prep(
    const float* __restrict__ x, const float* __restrict__ w_off,
    const float* __restrict__ w_dcn,
    ushort* __restrict__ xt, ushort* __restrict__ pA1,
    ushort* __restrict__ pAc, ushort* __restrict__ pW)
{
    __shared__ ushort tile[16 * 66];
    const int bi = blockIdx.x;
    const int tid = threadIdx.x;
    if (bi < 1024) {
        const int b  = bi >> 9;
        const int f0 = (bi & 511) * 16;
        #pragma unroll
        for (int it = 0; it < 4; ++it) {
            int c = it * 16 + (tid >> 4), f = tid & 15;
            tile[f * 66 + c] = f2bf(x[((size_t)(b * 64 + c)) * DHW + f0 + f]);
        }
        __syncthreads();
        #pragma unroll
        for (int it = 0; it < 4; ++it) {
            int f = it * 4 + (tid >> 6), c = tid & 63;
            xt[((size_t)b * DHW + f0 + f) * 64 + c] = tile[f * 66 + c];
        }
    } else {
        int t0 = (bi - 1024) * 256 + tid;
        const int stride = 32 * 256;
        for (int i = t0; i < 27 * 2 * 7 * 512; i += stride) {
            int j = i & 7, l = (i >> 3) & 63, rest = i >> 9;
            int m = rest % 7, ch = (rest / 7) & 1, tap = rest / 14;
            int co = m * 16 + (l & 15);
            int ci = ch * 32 + (l >> 4) * 8 + j;
            pA1[i] = (co < COFF) ? f2bf(w_off[(co * 67 + ci) * 27 + tap]) : (ushort)0;
        }
        for (int i = t0; i < 3 * 7 * 512; i += stride) {
            int j = i & 7, l = (i >> 3) & 63, rest = i >> 9;
            int m = rest % 7, t = rest / 7;
            int co = m * 16 + (l & 15);
            int flatk = t * 32 + (l >> 4) * 8 + j;
            ushort v = 0;
            if (co < COFF && flatk < 81) {
                int cc = flatk / 27, tap = flatk % 27;
                v = f2bf(w_off[(co * 67 + 64 + cc) * 27 + tap]);
            }
            pAc[i] = v;
        }
        for (int i = t0; i < 27 * 2 * 4 * 512; i += stride) {
            int j = i & 7, l = (i >> 3) & 63;
            int m = (i >> 9) & 3, ch = (i >> 11) & 1, k = i >> 12;
            int o = m * 16 + (l & 15);
            int c = ch * 32 + (l >> 4) * 8 + j;
            pW[i] = f2bf(w_dcn[(o * 64 + c) * 27 + k]);
        }
    }
}

// ---------------- kernel B1: offset conv -> pred (bf16, HBM) ---------------
__global__ __launch_bounds__(512, 4) void k_conv(
    const ushort* __restrict__ xt, const ushort* __restrict__ pA1,
    const ushort* __restrict__ pAc, const float* __restrict__ b_off,
    ushort* __restrict__ predg)
{
    __shared__ __align__(16) char smem[57344];   // red1 uint2[(sw*14+i)*64+lane]

    const int bi   = blockIdx.x;
    const int b    = bi >> 8;
    const int sp32 = bi & 255;
    const int d    = sp32 >> 5;
    const int h    = sp32 & 31;
    const int spg  = sp32 * 32;
    const int tid  = threadIdx.x;
    const int wv = tid >> 6, lane = tid & 63, q = lane >> 4, r16 = lane & 15;
    const ushort* __restrict__ xb = xt + (size_t)b * DHW * 64;

    f32x4 acc1[14] = {};      // [m*2 + pt]
    for (int c = wv; c < 57; c += 8) {
        bf16x8 bf[2];
        const ushort* pa;
        if (c < 54) {
            int tap = c >> 1, ch = c & 1;
            int dz = tap / 9, rem9 = tap - dz * 9, dy = rem9 / 3, dx = rem9 - dy * 3;
            int zz = d + dz - 1, yy = h + dy - 1;
            int basepos = (zz << 10) + (yy << 5);
            bool okzy = ((unsigned)zz < 8u) & ((unsigned)yy < 32u);
            #pragma unroll
            for (int pt = 0; pt < 2; ++pt) {
                int xx = pt * 16 + r16 + dx - 1;
                bool ok = okzy & ((unsigned)xx < 32u);
                bf16x8 tv = {};
                if (ok) tv = *(const bf16x8*)(xb + (size_t)(basepos + xx) * 64
                                              + ch * 32 + q * 8);
                bf[pt] = tv;
            }
            pa = pA1 + (size_t)((tap * 2 + ch) * 7) * 512 + lane * 8;
        } else {
            int t = c - 54;
            #pragma unroll
            for (int pt = 0; pt < 2; ++pt) {
                bf16x8 bt;
                #pragma unroll
                for (int j = 0; j < 8; ++j) {
                    int flatk = t * 32 + q * 8 + j;
                    int cc = flatk / 27, tap = flatk % 27;
                    int dz = tap / 9, rem9 = tap - dz * 9, dy = rem9 / 3, dx = rem9 - dy * 3;
                    int zz = d + dz - 1, yy = h + dy - 1, xx = pt * 16 + r16 + dx - 1;
                    bool ok = (flatk < 81) & ((unsigned)zz < 8u) & ((unsigned)yy < 32u)
                              & ((unsigned)xx < 32u);
                    float val = 0.f;
                    if (ok)
                        val = (cc == 0) ? (-1.f + (2.f / 7.f) * (float)zz)
                            : (cc == 1) ? (-1.f + (2.f / 31.f) * (float)yy)
                                        : (-1.f + (2.f / 31.f) * (float)xx);
                    bt[j] = (short)f2bf(val);
                }
                bf[pt] = bt;
            }
            pa = pAc + (size_t)(t * 7) * 512 + lane * 8;
        }
        #pragma unroll
        for (int m = 0; m < 7; ++m) {
            bf16x8 af = *(const bf16x8*)(pa + m * 512);
            acc1[m * 2 + 0] = __builtin_amdgcn_mfma_f32_16x16x32_bf16(af, bf[0], acc1[m * 2 + 0], 0, 0, 0);
            acc1[m * 2 + 1] = __builtin_amdgcn_mfma_f32_16x16x32_bf16(af, bf[1], acc1[m * 2 + 1], 0, 0, 0);
        }
    }
    // distributed bf16-partial reduce across the 8 waves, write pred to HBM
    uint2* red1 = (uint2*)smem;
    #pragma unroll
    for (int i = 0; i < 14; ++i) {
        f32x4 s = acc1[i];
        uint2 pk2;
        pk2.x = (unsigned)f2bf(s[0]) | ((unsigned)f2bf(s[1]) << 16);
        pk2.y = (unsigned)f2bf(s[2]) | ((unsigned)f2bf(s[3]) << 16);
        red1[(wv * 14 + i) * 64 + lane] = pk2;
    }
    __syncthreads();
    ushort* __restrict__ predb = predg + (size_t)b * COFF * DHW + spg;
    for (int i = wv; i < 14; i += 8) {
        float s0 = 0.f, s1 = 0.f, s2 = 0.f, s3 = 0.f;
        #pragma unroll
        for (int sw = 0; sw < 8; ++sw) {
            uint2 v = red1[(sw * 14 + i) * 64 + lane];
            s0 += bf2f((unsigned short)(v.x & 0xffffu));
            s1 += bf2f((unsigned short)(v.x >> 16));
            s2 += bf2f((unsigned short)(v.y & 0xffffu));
            s3 += bf2f((unsigned short)(v.y >> 16));
        }
        int m = i >> 1, pt = i & 1;
        float sr[4] = {s0, s1, s2, s3};
        #pragma unroll
        for (int r = 0; r < 4; ++r) {
            int co = m * 16 + q * 4 + r;
            if (co < COFF)
                predb[(size_t)co * DHW + pt * 16 + r16] = f2bf(sr[r] + b_off[co]);
        }
    }
}

// ---------------- kernel B2: LDS-slab sample + GEMM (per ch-half) -----------
// block: 16 positions x one 32-ch half; 256 thr (4 waves = k-quarters)
// slab: 5z x 5y x 20x positions x 64B, slot-XOR swizzled; OOW -> global tag
__global__ __launch_bounds__(256, 3) void k_dcn3(
    const ushort* __restrict__ xt, const ushort* __restrict__ predg,
    const ushort* __restrict__ pW, const float* __restrict__ b_dcn,
    float* __restrict__ out)
{
    __shared__ __align__(16) char smem[53184];
    char*  slab = smem;                               // 32000 B
    uint4* cwi  = (uint4*)(smem + 32000);             // 13824 B  (red2 aliases)
    uint4* cww  = (uint4*)(smem + 45824);             //  6912 B
    unsigned char* tagb = (unsigned char*)(smem + 52736);  // 432 B

    const int bi   = blockIdx.x;
    const int ch2  = bi & 1;
    const int sp16 = (bi >> 1) & 511;
    const int b    = bi >> 10;
    const int d    = sp16 >> 6;
    const int h    = (sp16 >> 1) & 31;
    const int x0   = (sp16 & 1) * 16;
    const int spg  = sp16 * 16;
    const int tid  = threadIdx.x;
    const int wv = tid >> 6, lane = tid & 63, q = lane >> 4, r16 = lane & 15;
    const ushort* __restrict__ xb = xt + (size_t)b * DHW * 64;
    const ushort* __restrict__ predb = predg + (size_t)b * COFF * DHW + spg;

    // ---- phase A: fill slab (500 positions x 4 slots of 16B) ----
    for (int idx = tid; idx < 2000; idx += 256) {
        int pos = idx >> 2, slot = idx & 3;
        int sz = pos / 100, rem = pos - sz * 100, sy = rem / 20, sx = rem - sy * 20;
        int gz = d - 2 + sz, gy = h - 2 + sy, gx = x0 - 2 + sx;
        uint4 v = {};
        if (((unsigned)gz < 8u) && ((unsigned)gy < 32u) && ((unsigned)gx < 32u))
            v = *(const uint4*)(xb + (size_t)((gz << 10) + (gy << 5) + gx) * 64
                                + ch2 * 32 + slot * 8);
        *(uint4*)(slab + pos * 64 + ((slot ^ (pos & 3)) << 4)) = v;
    }

    // ---- phase B: corner tables (27 k x 16 p) ----
    for (int kp = tid; kp < 432; kp += 256) {
        int k = kp >> 4, p = kp & 15;
        float offz = bf2f(predb[(k * 3 + 0) * DHW + p]);
        float offy = bf2f(predb[(k * 3 + 1) * DHW + p]);
        float offx = bf2f(predb[(k * 3 + 2) * DHW + p]);
        float av   = bf2f(predb[(81 + k) * DHW + p]);
        float alpha = 1.f / (1.f + __expf(-av));
        int kz = k / 9, rem = k - kz * 9, ky = rem / 3, kx = rem - ky * 3;
        float pz = (float)(d + kz - 1) + offz;
        float py = (float)(h + ky - 1) + offy;
        float px = (float)(x0 + p + kx - 1) + offx;
        float fz = floorf(pz), fy = floorf(py), fx = floorf(px);
        float tz = pz - fz, ty = py - fy, tx = px - fx;
        int iz0 = (int)fz, iy0 = (int)fy, ix0 = (int)fx;
        unsigned glob[8], linb[8]; float wgts[8];
        bool anyoow = false;
        #pragma unroll
        for (int c8 = 0; c8 < 8; ++c8) {
            int czi = c8 >> 2, cyi = (c8 >> 1) & 1, cxi = c8 & 1;
            int iz = iz0 + czi, iy = iy0 + cyi, ix = ix0 + cxi;
            float wz = czi ? tz : 1.f - tz;
            float wy = cyi ? ty : 1.f - ty;
            float wx = cxi ? tx : 1.f - tx;
            bool ok = ((unsigned)iz < 8u) && ((unsigned)iy < 32u) && ((unsigned)ix < 32u);
            int szw = iz - d + 2, syw = iy - h + 2, sxw = ix - x0 + 2;
            bool inw = ((unsigned)szw < 5u) && ((unsigned)syw < 5u) && ((unsigned)sxw < 20u);
            if (ok && !inw) anyoow = true;
            wgts[c8] = ok ? wz * wy * wx * alpha : 0.f;
            glob[c8] = ok ? ((unsigned)((iz << 10) + (iy << 5) + ix) << 7) : 0u;
            int szc = szw < 0 ? 0 : (szw > 4 ? 4 : szw);
            int syc = syw < 0 ? 0 : (syw > 4 ? 4 : syw);
            int sxc = sxw < 0 ? 0 : (sxw > 19 ? 19 : sxw);
            linb[c8] = (unsigned)(((szc * 5 + syc) * 20 + sxc) << 6);
        }
        uint4 w0_, w1_;
        if (anyoow) {
            w0_ = make_uint4(glob[0], glob[1], glob[2], glob[3]);
            w1_ = make_uint4(glob[4], glob[5], glob[6], glob[7]);
        } else {
            w0_ = make_uint4(linb[0], linb[1], linb[2], linb[3]);
            w1_ = make_uint4(linb[4], linb[5], linb[6], linb[7]);
        }
        cwi[(k * 2 + 0) * 16 + p] = w0_;
        cwi[(k * 2 + 1) * 16 + p] = w1_;
        cww[k * 16 + p] = make_uint4(
            (unsigned)f2bf(wgts[0]) | ((unsigned)f2bf(wgts[1]) << 16),
            (unsigned)f2bf(wgts[2]) | ((unsigned)f2bf(wgts[3]) << 16),
            (unsigned)f2bf(wgts[4]) | ((unsigned)f2bf(wgts[5]) << 16),
            (unsigned)f2bf(wgts[6]) | ((unsigned)f2bf(wgts[7]) << 16));
        tagb[kp] = anyoow ? 1 : 0;
    }
    __syncthreads();

    // ---- phase C: sample from slab + in-wave transpose + MFMA ----
    const int pr = lane >> 2, cg = lane & 3;
    const char* __restrict__ xbG = (const char*)xb + ch2 * 64 + cg * 16;
    const int baddr = (r16 * 4 + q) << 2;     // bpermute source lane r16*4+q
    const unsigned cgsh = (unsigned)(cg << 4);
    f32x4 acc2[4] = {};
    const int kbeg = wv * 7;
    const int kend = (kbeg + 7 < 27) ? (kbeg + 7) : 27;
    for (int k = kbeg; k < kend; ++k) {
        uint4 wq = cww[k * 16 + pr];
        uint4 i0 = cwi[(k * 2 + 0) * 16 + pr];
        uint4 i1 = cwi[(k * 2 + 1) * 16 + pr];
        unsigned iv[8] = {i0.x, i0.y, i0.z, i0.w, i1.x, i1.y, i1.z, i1.w};
        bool tg = tagb[k * 16 + pr] != 0;
        uint4 xv[8];
        if (!tg) {
            #pragma unroll
            for (int c8 = 0; c8 < 8; ++c8) {
                unsigned a = iv[c8];
                unsigned addr = a + (cgsh ^ ((a >> 2) & 0x30u));
                xv[c8] = *(const uint4*)(slab + addr);
            }
        }
        if (tg) {
            #pragma unroll
            for (int c8 = 0; c8 < 8; ++c8)
                xv[c8] = *(const uint4*)(xbG + iv[c8]);
        }
        unsigned wp[4] = {wq.x, wq.y, wq.z, wq.w};
        float sa[8] = {};
        #pragma unroll
        for (int cp = 0; cp < 4; ++cp) {
            unsigned ua[4] = {xv[cp * 2 + 0].x, xv[cp * 2 + 0].y, xv[cp * 2 + 0].z, xv[cp * 2 + 0].w};
            unsigned ub[4] = {xv[cp * 2 + 1].x, xv[cp * 2 + 1].y, xv[cp * 2 + 1].z, xv[cp * 2 + 1].w};
            #pragma unroll
            for (int dw = 0; dw < 4; ++dw) {
                unsigned plo = __builtin_amdgcn_perm(ub[dw], ua[dw], 0x05040100u);
                unsigned phi = __builtin_amdgcn_perm(ub[dw], ua[dw], 0x07060302u);
                sa[dw * 2 + 0] = dot2bf(plo, wp[cp], sa[dw * 2 + 0]);
                sa[dw * 2 + 1] = dot2bf(phi, wp[cp], sa[dw * 2 + 1]);
            }
        }
        unsigned pk0 = (unsigned)f2bf(sa[0]) | ((unsigned)f2bf(sa[1]) << 16);
        unsigned pk1 = (unsigned)f2bf(sa[2]) | ((unsigned)f2bf(sa[3]) << 16);
        unsigned pk2 = (unsigned)f2bf(sa[4]) | ((unsigned)f2bf(sa[5]) << 16);
        unsigned pk3 = (unsigned)f2bf(sa[6]) | ((unsigned)f2bf(sa[7]) << 16);
        uint4 bd;
        bd.x = (unsigned)__builtin_amdgcn_ds_bpermute(baddr, (int)pk0);
        bd.y = (unsigned)__builtin_amdgcn_ds_bpermute(baddr, (int)pk1);
        bd.z = (unsigned)__builtin_amdgcn_ds_bpermute(baddr, (int)pk2);
        bd.w = (unsigned)__builtin_amdgcn_ds_bpermute(baddr, (int)pk3);
        bf16x8 bfrag = __builtin_bit_cast(bf16x8, bd);
        const ushort* pwk = pW + (size_t)((k * 2 + ch2) * 4) * 512 + lane * 8;
        #pragma unroll
        for (int m = 0; m < 4; ++m)
            acc2[m] = __builtin_amdgcn_mfma_f32_16x16x32_bf16(
                *(const bf16x8*)(pwk + m * 512), bfrag, acc2[m], 0, 0, 0);
    }

    // ---- epilogue: reduce over k-quarter waves, atomic add ch-halves ----
    __syncthreads();                 // cwi dead; alias red2
    f32x4* red2 = (f32x4*)(smem + 32000);
    #pragma unroll
    for (int m = 0; m < 4; ++m)
        red2[(wv * 4 + m) * 64 + lane] = acc2[m];
    __syncthreads();
    {
        const int mo = wv;          // wave wv stores m = wv
        f32x4 s = red2[(0 * 4 + mo) * 64 + lane]
                + red2[(1 * 4 + mo) * 64 + lane]
                + red2[(2 * 4 + mo) * 64 + lane]
                + red2[(3 * 4 + mo) * 64 + lane];
        float* __restrict__ outb = out + (size_t)b * 64 * DHW + spg;
        #pragma unroll
        for (int r = 0; r < 4; ++r) {
            int o = mo * 16 + q * 4 + r;
            float v = s[r] + (ch2 == 0 ? b_dcn[o] : 0.f);
            atomicAdd(&outb[(size_t)o * DHW + r16], v);
        }
    }
}

extern "C" void kernel_launch(void* const* d_in, const int* in_sizes, int n_in,
                              void* d_out, int out_size, void* d_ws, size_t ws_size,
                              hipStream_t stream) {
    const float* x     = (const float*)d_in[0];
    const float* w_off = (const float*)d_in[1];
    const float* b_off = (const float*)d_in[2];
    const float* w_dcn = (const float*)d_in[3];
    const float* b_dcn = (const float*)d_in[4];
    float* out = (float*)d_out;

    ushort* xt   = (ushort*)d_ws;                          // 2,097,152 B
    ushort* pA1  = (ushort*)((char*)d_ws + 2097152);       //   387,072 B
    ushort* pAc  = (ushort*)((char*)d_ws + 2484224);       //    21,504 B
    ushort* pW   = (ushort*)((char*)d_ws + 2505728);       //   221,184 B
    ushort* pred = (ushort*)((char*)d_ws + 2726912);       // 3,538,944 B

    hipMemsetAsync(out, 0, (size_t)out_size * sizeof(float), stream);
    k_prep<<<1056, 256, 0, stream>>>(x, w_off, w_dcn, xt, pA1, pAc, pW);
    k_conv<<<512, 512, 0, stream>>>(xt, pA1, pAc, b_off, pred);
    k_dcn3<<<2048, 256, 0, stream>>>(xt, pred, pW, b_dcn, out);
}

// Round 11
// 77.733 us; speedup vs baseline: 1.0615x; 1.0615x over previous
//
#include <hip/hip_runtime.h>

#define DHW  8192
#define COFF 108

typedef __attribute__((ext_vector_type(8))) short bf16x8;
typedef __attribute__((ext_vector_type(4))) float f32x4;
typedef __bf16 bfv2 __attribute__((ext_vector_type(2)));

__device__ inline unsigned short f2bf(float f) {
    unsigned u = __float_as_uint(f);
    u += 0x7fffu + ((u >> 16) & 1u);     // RNE
    return (unsigned short)(u >> 16);
}
__device__ inline float bf2f(unsigned short h) {
    return __uint_as_float(((unsigned)h) << 16);
}

// dot2: c += a.lo*b.lo + a.hi*b.hi  (bf16 pairs packed in dwords)
__device__ inline float dot2bf(unsigned a, unsigned b, float c) {
#if defined(__has_builtin) && __has_builtin(__builtin_amdgcn_fdot2_f32_bf16)
    return __builtin_amdgcn_fdot2_f32_bf16(__builtin_bit_cast(bfv2, a),
                                           __builtin_bit_cast(bfv2, b), c, false);
#else
    c += __uint_as_float(a << 16) * __uint_as_float(b << 16);
    c += __uint_as_float(a & 0xffff0000u) * __uint_as_float(b & 0xffff0000u);
    return c;
#endif
}

// ---------------- kernel A: out-zero + xt transpose + weight packing --------
__global__ __launch_bounds__(256) void k_prep(
    const float* __restrict__ x, const float* __restrict__ w_off,
    const float* __restrict__ w_dcn,
    ushort* __restrict__ xt, ushort* __restrict__ pA1,
    ushort* __restrict__ pAc, ushort* __restrict__ pW,
    float* __restrict__ outz)
{
    __shared__ ushort tile[16 * 66];
    const int bi = blockIdx.x;
    const int tid = threadIdx.x;
    // zero the output (replaces the pathological hipMemsetAsync)
    {
        const int nvec = 2 * 64 * DHW / 4;            // 262144 float4
        float4 z = {0.f, 0.f, 0.f, 0.f};
        for (int i = bi * 256 + tid; i < nvec; i += gridDim.x * 256)
            ((float4*)outz)[i] = z;
    }
    if (bi < 1024) {
        const int b  = bi >> 9;
        const int f0 = (bi & 511) * 16;
        #pragma unroll
        for (int it = 0; it < 4; ++it) {
            int c = it * 16 + (tid >> 4), f = tid & 15;
            tile[f * 66 + c] = f2bf(x[((size_t)(b * 64 + c)) * DHW + f0 + f]);
        }
        __syncthreads();
        #pragma unroll
        for (int it = 0; it < 4; ++it) {
            int f = it * 4 + (tid >> 6), c = tid & 63;
            xt[((size_t)b * DHW + f0 + f) * 64 + c] = tile[f * 66 + c];
        }
    } else {
        int t0 = (bi - 1024) * 256 + tid;
        const int stride = 32 * 256;
        for (int i = t0; i < 27 * 2 * 7 * 512; i += stride) {
            int j = i & 7, l = (i >> 3) & 63, rest = i >> 9;
            int m = rest % 7, ch = (rest / 7) & 1, tap = rest / 14;
            int co = m * 16 + (l & 15);
            int ci = ch * 32 + (l >> 4) * 8 + j;
            pA1[i] = (co < COFF) ? f2bf(w_off[(co * 67 + ci) * 27 + tap]) : (ushort)0;
        }
        for (int i = t0; i < 3 * 7 * 512; i += stride) {
            int j = i & 7, l = (i >> 3) & 63, rest = i >> 9;
            int m = rest % 7, t = rest / 7;
            int co = m * 16 + (l & 15);
            int flatk = t * 32 + (l >> 4) * 8 + j;
            ushort v = 0;
            if (co < COFF && flatk < 81) {
                int cc = flatk / 27, tap = flatk % 27;
                v = f2bf(w_off[(co * 67 + 64 + cc) * 27 + tap]);
            }
            pAc[i] = v;
        }
        for (int i = t0; i < 27 * 2 * 4 * 512; i += stride) {
            int j = i & 7, l = (i >> 3) & 63;
            int m = (i >> 9) & 3, ch = (i >> 11) & 1, k = i >> 12;
            int o = m * 16 + (l & 15);
            int c = ch * 32 + (l >> 4) * 8 + j;
            pW[i] = f2bf(w_dcn[(o * 64 + c) * 27 + k]);
        }
    }
}

// ---------------- kernel B1: offset conv -> pred (bf16, HBM) ---------------
__global__ __launch_bounds__(512, 4) void k_conv(
    const ushort* __restrict__ xt, const ushort* __restrict__ pA1,
    const ushort* __restrict__ pAc, const float* __restrict__ b_off,
    ushort* __restrict__ predg)
{
    __shared__ __align__(16) char smem[57344];   // red1 uint2[(sw*14+i)*64+lane]

    const int bi   = blockIdx.x;
    const int b    = bi >> 8;
    const int sp32 = bi & 255;
    const int d    = sp32 >> 5;
    const int h    = sp32 & 31;
    const int spg  = sp32 * 32;
    const int tid  = threadIdx.x;
    const int wv = tid >> 6, lane = tid & 63, q = lane >> 4, r16 = lane & 15;
    const ushort* __restrict__ xb = xt + (size_t)b * DHW * 64;

    f32x4 acc1[14] = {};      // [m*2 + pt]
    for (int c = wv; c < 57; c += 8) {
        bf16x8 bf[2];
        const ushort* pa;
        if (c < 54) {
            int tap = c >> 1, ch = c & 1;
            int dz = tap / 9, rem9 = tap - dz * 9, dy = rem9 / 3, dx = rem9 - dy * 3;
            int zz = d + dz - 1, yy = h + dy - 1;
            int basepos = (zz << 10) + (yy << 5);
            bool okzy = ((unsigned)zz < 8u) & ((unsigned)yy < 32u);
            #pragma unroll
            for (int pt = 0; pt < 2; ++pt) {
                int xx = pt * 16 + r16 + dx - 1;
                bool ok = okzy & ((unsigned)xx < 32u);
                bf16x8 tv = {};
                if (ok) tv = *(const bf16x8*)(xb + (size_t)(basepos + xx) * 64
                                              + ch * 32 + q * 8);
                bf[pt] = tv;
            }
            pa = pA1 + (size_t)((tap * 2 + ch) * 7) * 512 + lane * 8;
        } else {
            int t = c - 54;
            #pragma unroll
            for (int pt = 0; pt < 2; ++pt) {
                bf16x8 bt;
                #pragma unroll
                for (int j = 0; j < 8; ++j) {
                    int flatk = t * 32 + q * 8 + j;
                    int cc = flatk / 27, tap = flatk % 27;
                    int dz = tap / 9, rem9 = tap - dz * 9, dy = rem9 / 3, dx = rem9 - dy * 3;
                    int zz = d + dz - 1, yy = h + dy - 1, xx = pt * 16 + r16 + dx - 1;
                    bool ok = (flatk < 81) & ((unsigned)zz < 8u) & ((unsigned)yy < 32u)
                              & ((unsigned)xx < 32u);
                    float val = 0.f;
                    if (ok)
                        val = (cc == 0) ? (-1.f + (2.f / 7.f) * (float)zz)
                            : (cc == 1) ? (-1.f + (2.f / 31.f) * (float)yy)
                                        : (-1.f + (2.f / 31.f) * (float)xx);
                    bt[j] = (short)f2bf(val);
                }
                bf[pt] = bt;
            }
            pa = pAc + (size_t)(t * 7) * 512 + lane * 8;
        }
        #pragma unroll
        for (int m = 0; m < 7; ++m) {
            bf16x8 af = *(const bf16x8*)(pa + m * 512);
            acc1[m * 2 + 0] = __builtin_amdgcn_mfma_f32_16x16x32_bf16(af, bf[0], acc1[m * 2 + 0], 0, 0, 0);
            acc1[m * 2 + 1] = __builtin_amdgcn_mfma_f32_16x16x32_bf16(af, bf[1], acc1[m * 2 + 1], 0, 0, 0);
        }
    }
    // distributed bf16-partial reduce across the 8 waves, write pred to HBM
    uint2* red1 = (uint2*)smem;
    #pragma unroll
    for (int i = 0; i < 14; ++i) {
        f32x4 s = acc1[i];
        uint2 pk2;
        pk2.x = (unsigned)f2bf(s[0]) | ((unsigned)f2bf(s[1]) << 16);
        pk2.y = (unsigned)f2bf(s[2]) | ((unsigned)f2bf(s[3]) << 16);
        red1[(wv * 14 + i) * 64 + lane] = pk2;
    }
    __syncthreads();
    ushort* __restrict__ predb = predg + (size_t)b * COFF * DHW + spg;
    for (int i = wv; i < 14; i += 8) {
        float s0 = 0.f, s1 = 0.f, s2 = 0.f, s3 = 0.f;
        #pragma unroll
        for (int sw = 0; sw < 8; ++sw) {
            uint2 v = red1[(sw * 14 + i) * 64 + lane];
            s0 += bf2f((unsigned short)(v.x & 0xffffu));
            s1 += bf2f((unsigned short)(v.x >> 16));
            s2 += bf2f((unsigned short)(v.y & 0xffffu));
            s3 += bf2f((unsigned short)(v.y >> 16));
        }
        int m = i >> 1, pt = i & 1;
        float sr[4] = {s0, s1, s2, s3};
        #pragma unroll
        for (int r = 0; r < 4; ++r) {
            int co = m * 16 + q * 4 + r;
            if (co < COFF)
                predb[(size_t)co * DHW + pt * 16 + r16] = f2bf(sr[r] + b_off[co]);
        }
    }
}

// ---------------- kernel B2: LDS-slab sample + GEMM (per ch-half) -----------
// block: 16 positions x one 32-ch half; 256 thr (4 waves = k-quarters)
// slab: 5z x 5y x 20x positions x 64B, slot-XOR swizzled; OOW -> global tag
__global__ __launch_bounds__(256, 3) void k_dcn3(
    const ushort* __restrict__ xt, const ushort* __restrict__ predg,
    const ushort* __restrict__ pW, const float* __restrict__ b_dcn,
    float* __restrict__ out)
{
    __shared__ __align__(16) char smem[53184];
    char*  slab = smem;                               // 32000 B
    uint4* cwi  = (uint4*)(smem + 32000);             // 13824 B  (red2 aliases)
    uint4* cww  = (uint4*)(smem + 45824);             //  6912 B
    unsigned char* tagb = (unsigned char*)(smem + 52736);  // 432 B

    const int bi   = blockIdx.x;
    const int ch2  = bi & 1;
    const int sp16 = (bi >> 1) & 511;
    const int b    = bi >> 10;
    const int d    = sp16 >> 6;
    const int h    = (sp16 >> 1) & 31;
    const int x0   = (sp16 & 1) * 16;
    const int spg  = sp16 * 16;
    const int tid  = threadIdx.x;
    const int wv = tid >> 6, lane = tid & 63, q = lane >> 4, r16 = lane & 15;
    const ushort* __restrict__ xb = xt + (size_t)b * DHW * 64;
    const ushort* __restrict__ predb = predg + (size_t)b * COFF * DHW + spg;

    // ---- phase A: fill slab (500 positions x 4 slots of 16B) ----
    for (int idx = tid; idx < 2000; idx += 256) {
        int pos = idx >> 2, slot = idx & 3;
        int sz = pos / 100, rem = pos - sz * 100, sy = rem / 20, sx = rem - sy * 20;
        int gz = d - 2 + sz, gy = h - 2 + sy, gx = x0 - 2 + sx;
        uint4 v = {};
        if (((unsigned)gz < 8u) && ((unsigned)gy < 32u) && ((unsigned)gx < 32u))
            v = *(const uint4*)(xb + (size_t)((gz << 10) + (gy << 5) + gx) * 64
                                + ch2 * 32 + slot * 8);
        *(uint4*)(slab + pos * 64 + ((slot ^ (pos & 3)) << 4)) = v;
    }

    // ---- phase B: corner tables (27 k x 16 p) ----
    for (int kp = tid; kp < 432; kp += 256) {
        int k = kp >> 4, p = kp & 15;
        float offz = bf2f(predb[(k * 3 + 0) * DHW + p]);
        float offy = bf2f(predb[(k * 3 + 1) * DHW + p]);
        float offx = bf2f(predb[(k * 3 + 2) * DHW + p]);
        float av   = bf2f(predb[(81 + k) * DHW + p]);
        float alpha = 1.f / (1.f + __expf(-av));
        int kz = k / 9, rem = k - kz * 9, ky = rem / 3, kx = rem - ky * 3;
        float pz = (float)(d + kz - 1) + offz;
        float py = (float)(h + ky - 1) + offy;
        float px = (float)(x0 + p + kx - 1) + offx;
        float fz = floorf(pz), fy = floorf(py), fx = floorf(px);
        float tz = pz - fz, ty = py - fy, tx = px - fx;
        int iz0 = (int)fz, iy0 = (int)fy, ix0 = (int)fx;
        unsigned glob[8], linb[8]; float wgts[8];
        bool anyoow = false;
        #pragma unroll
        for (int c8 = 0; c8 < 8; ++c8) {
            int czi = c8 >> 2, cyi = (c8 >> 1) & 1, cxi = c8 & 1;
            int iz = iz0 + czi, iy = iy0 + cyi, ix = ix0 + cxi;
            float wz = czi ? tz : 1.f - tz;
            float wy = cyi ? ty : 1.f - ty;
            float wx = cxi ? tx : 1.f - tx;
            bool ok = ((unsigned)iz < 8u) && ((unsigned)iy < 32u) && ((unsigned)ix < 32u);
            int szw = iz - d + 2, syw = iy - h + 2, sxw = ix - x0 + 2;
            bool inw = ((unsigned)szw < 5u) && ((unsigned)syw < 5u) && ((unsigned)sxw < 20u);
            if (ok && !inw) anyoow = true;
            wgts[c8] = ok ? wz * wy * wx * alpha : 0.f;
            glob[c8] = ok ? ((unsigned)((iz << 10) + (iy << 5) + ix) << 7) : 0u;
            int szc = szw < 0 ? 0 : (szw > 4 ? 4 : szw);
            int syc = syw < 0 ? 0 : (syw > 4 ? 4 : syw);
            int sxc = sxw < 0 ? 0 : (sxw > 19 ? 19 : sxw);
            linb[c8] = (unsigned)(((szc * 5 + syc) * 20 + sxc) << 6);
        }
        uint4 w0_, w1_;
        if (anyoow) {
            w0_ = make_uint4(glob[0], glob[1], glob[2], glob[3]);
            w1_ = make_uint4(glob[4], glob[5], glob[6], glob[7]);
        } else {
            w0_ = make_uint4(linb[0], linb[1], linb[2], linb[3]);
            w1_ = make_uint4(linb[4], linb[5], linb[6], linb[7]);
        }
        cwi[(k * 2 + 0) * 16 + p] = w0_;
        cwi[(k * 2 + 1) * 16 + p] = w1_;
        cww[k * 16 + p] = make_uint4(
            (unsigned)f2bf(wgts[0]) | ((unsigned)f2bf(wgts[1]) << 16),
            (unsigned)f2bf(wgts[2]) | ((unsigned)f2bf(wgts[3]) << 16),
            (unsigned)f2bf(wgts[4]) | ((unsigned)f2bf(wgts[5]) << 16),
            (unsigned)f2bf(wgts[6]) | ((unsigned)f2bf(wgts[7]) << 16));
        tagb[kp] = anyoow ? 1 : 0;
    }
    __syncthreads();

    // ---- phase C: sample from slab + in-wave transpose + MFMA ----
    const int pr = lane >> 2, cg = lane & 3;
    const char* __restrict__ xbG = (const char*)xb + ch2 * 64 + cg * 16;
    const int baddr = (r16 * 4 + q) << 2;     // bpermute source lane r16*4+q
    const unsigned cgsh = (unsigned)(cg << 4);
    f32x4 acc2[4] = {};
    const int kbeg = wv * 7;
    const int kend = (kbeg + 7 < 27) ? (kbeg + 7) : 27;
    for (int k = kbeg; k < kend; ++k) {
        uint4 wq = cww[k * 16 + pr];
        uint4 i0 = cwi[(k * 2 + 0) * 16 + pr];
        uint4 i1 = cwi[(k * 2 + 1) * 16 + pr];
        unsigned iv[8] = {i0.x, i0.y, i0.z, i0.w, i1.x, i1.y, i1.z, i1.w};
        bool tg = tagb[k * 16 + pr] != 0;
        uint4 xv[8];
        if (!tg) {
            #pragma unroll
            for (int c8 = 0; c8 < 8; ++c8) {
                unsigned a = iv[c8];
                unsigned addr = a + (cgsh ^ ((a >> 2) & 0x30u));
                xv[c8] = *(const uint4*)(slab + addr);
            }
        }
        if (tg) {
            #pragma unroll
            for (int c8 = 0; c8 < 8; ++c8)
                xv[c8] = *(const uint4*)(xbG + iv[c8]);
        }
        unsigned wp[4] = {wq.x, wq.y, wq.z, wq.w};
        float sa[8] = {};
        #pragma unroll
        for (int cp = 0; cp < 4; ++cp) {
            unsigned ua[4] = {xv[cp * 2 + 0].x, xv[cp * 2 + 0].y, xv[cp * 2 + 0].z, xv[cp * 2 + 0].w};
            unsigned ub[4] = {xv[cp * 2 + 1].x, xv[cp * 2 + 1].y, xv[cp * 2 + 1].z, xv[cp * 2 + 1].w};
            #pragma unroll
            for (int dw = 0; dw < 4; ++dw) {
                unsigned plo = __builtin_amdgcn_perm(ub[dw], ua[dw], 0x05040100u);
                unsigned phi = __builtin_amdgcn_perm(ub[dw], ua[dw], 0x07060302u);
                sa[dw * 2 + 0] = dot2bf(plo, wp[cp], sa[dw * 2 + 0]);
                sa[dw * 2 + 1] = dot2bf(phi, wp[cp], sa[dw * 2 + 1]);
            }
        }
        unsigned pk0 = (unsigned)f2bf(sa[0]) | ((unsigned)f2bf(sa[1]) << 16);
        unsigned pk1 = (unsigned)f2bf(sa[2]) | ((unsigned)f2bf(sa[3]) << 16);
        unsigned pk2 = (unsigned)f2bf(sa[4]) | ((unsigned)f2bf(sa[5]) << 16);
        unsigned pk3 = (unsigned)f2bf(sa[6]) | ((unsigned)f2bf(sa[7]) << 16);
        uint4 bd;
        bd.x = (unsigned)__builtin_amdgcn_ds_bpermute(baddr, (int)pk0);
        bd.y = (unsigned)__builtin_amdgcn_ds_bpermute(baddr, (int)pk1);
        bd.z = (unsigned)__builtin_amdgcn_ds_bpermute(baddr, (int)pk2);
        bd.w = (unsigned)__builtin_amdgcn_ds_bpermute(baddr, (int)pk3);
        bf16x8 bfrag = __builtin_bit_cast(bf16x8, bd);
        const ushort* pwk = pW + (size_t)((k * 2 + ch2) * 4) * 512 + lane * 8;
        #pragma unroll
        for (int m = 0; m < 4; ++m)
            acc2[m] = __builtin_amdgcn_mfma_f32_16x16x32_bf16(
                *(const bf16x8*)(pwk + m * 512), bfrag, acc2[m], 0, 0, 0);
    }

    // ---- epilogue: reduce over k-quarter waves, atomic add ch-halves ----
    __syncthreads();                 // cwi dead; alias red2
    f32x4* red2 = (f32x4*)(smem + 32000);
    #pragma unroll
    for (int m = 0; m < 4; ++m)
        red2[(wv * 4 + m) * 64 + lane] = acc2[m];
    __syncthreads();
    {
        const int mo = wv;          // wave wv stores m = wv
        f32x4 s = red2[(0 * 4 + mo) * 64 + lane]
                + red2[(1 * 4 + mo) * 64 + lane]
                + red2[(2 * 4 + mo) * 64 + lane]
                + red2[(3 * 4 + mo) * 64 + lane];
        float* __restrict__ outb = out + (size_t)b * 64 * DHW + spg;
        #pragma unroll
        for (int r = 0; r < 4; ++r) {
            int o = mo * 16 + q * 4 + r;
            float v = s[r] + (ch2 == 0 ? b_dcn[o] : 0.f);
            atomicAdd(&outb[(size_t)o * DHW + r16], v);
        }
    }
}

extern "C" void kernel_launch(void* const* d_in, const int* in_sizes, int n_in,
                              void* d_out, int out_size, void* d_ws, size_t ws_size,
                              hipStream_t stream) {
    const float* x     = (const float*)d_in[0];
    const float* w_off = (const float*)d_in[1];
    const float* b_off = (const float*)d_in[2];
    const float* w_dcn = (const float*)d_in[3];
    const float* b_dcn = (const float*)d_in[4];
    float* out = (float*)d_out;

    ushort* xt   = (ushort*)d_ws;                          // 2,097,152 B
    ushort* pA1  = (ushort*)((char*)d_ws + 2097152);       //   387,072 B
    ushort* pAc  = (ushort*)((char*)d_ws + 2484224);       //    21,504 B
    ushort* pW   = (ushort*)((char*)d_ws + 2505728);       //   221,184 B
    ushort* pred = (ushort*)((char*)d_ws + 2726912);       // 3,538,944 B

    k_prep<<<1056, 256, 0, stream>>>(x, w_off, w_dcn, xt, pA1, pAc, pW, out);
    k_conv<<<512, 512, 0, stream>>>(xt, pA1, pAc, b_off, pred);
    k_dcn3<<<2048, 256, 0, stream>>>(xt, pred, pW, b_dcn, out);
}

// Round 14
// 60.626 us; speedup vs baseline: 1.3611x; 1.2822x over previous
//
#include <hip/hip_runtime.h>
#include <hip/hip_bf16.h>

#define DHW  8192
#define COFF 108

typedef __attribute__((ext_vector_type(8))) short bf16x8;
typedef __attribute__((ext_vector_type(4))) float f32x4;
typedef __bf16 bfv2 __attribute__((ext_vector_type(2)));

__device__ inline unsigned short f2bf(float f) {
    unsigned u = __float_as_uint(f);
    u += 0x7fffu + ((u >> 16) & 1u);     // RNE
    return (unsigned short)(u >> 16);
}
__device__ inline float bf2f(unsigned short h) {
    return __uint_as_float(((unsigned)h) << 16);
}
// packed f32->bf16 RNE via HIP intrinsic (compiler picks the HW instruction)
__device__ inline unsigned pk2bf(float lo, float hi) {
    __hip_bfloat162 t = __float22bfloat162_rn(float2{lo, hi});
    unsigned short a = __bfloat16_as_ushort(t.x);
    unsigned short b = __bfloat16_as_ushort(t.y);
    return (unsigned)a | ((unsigned)b << 16);
}

// dot2: c += a.lo*b.lo + a.hi*b.hi  (bf16 pairs packed in dwords)
__device__ inline float dot2bf(unsigned a, unsigned b, float c) {
#if defined(__has_builtin) && __has_builtin(__builtin_amdgcn_fdot2_f32_bf16)
    return __builtin_amdgcn_fdot2_f32_bf16(__builtin_bit_cast(bfv2, a),
                                           __builtin_bit_cast(bfv2, b), c, false);
#else
    c += __uint_as_float(a << 16) * __uint_as_float(b << 16);
    c += __uint_as_float(a & 0xffff0000u) * __uint_as_float(b & 0xffff0000u);
    return c;
#endif
}

// ---------------- kernel A: xt transpose + weight packing -------------------
__global__ __launch_bounds__(256) void k_prep(
    const float* __restrict__ x, const float* __restrict__ w_off,
    const float* __restrict__ w_dcn,
    ushort* __restrict__ xt, ushort* __restrict__ pA1,
    ushort* __restrict__ pAc, ushort* __restrict__ pW)
{
    __shared__ ushort tile[16 * 66];
    const int bi = blockIdx.x;
    const int tid = threadIdx.x;
    if (bi < 1024) {
        const int b  = bi >> 9;
        const int f0 = (bi & 511) * 16;
        #pragma unroll
        for (int it = 0; it < 4; ++it) {
            int c = it * 16 + (tid >> 4), f = tid & 15;
            tile[f * 66 + c] = f2bf(x[((size_t)(b * 64 + c)) * DHW + f0 + f]);
        }
        __syncthreads();
        #pragma unroll
        for (int it = 0; it < 4; ++it) {
            int f = it * 4 + (tid >> 6), c = tid & 63;
            xt[((size_t)b * DHW + f0 + f) * 64 + c] = tile[f * 66 + c];
        }
    } else {
        int t0 = (bi - 1024) * 256 + tid;
        const int stride = 32 * 256;
        for (int i = t0; i < 27 * 2 * 7 * 512; i += stride) {
            int j = i & 7, l = (i >> 3) & 63, rest = i >> 9;
            int m = rest % 7, ch = (rest / 7) & 1, tap = rest / 14;
            int co = m * 16 + (l & 15);
            int ci = ch * 32 + (l >> 4) * 8 + j;
            pA1[i] = (co < COFF) ? f2bf(w_off[(co * 67 + ci) * 27 + tap]) : (ushort)0;
        }
        for (int i = t0; i < 3 * 7 * 512; i += stride) {
            int j = i & 7, l = (i >> 3) & 63, rest = i >> 9;
            int m = rest % 7, t = rest / 7;
            int co = m * 16 + (l & 15);
            int flatk = t * 32 + (l >> 4) * 8 + j;
            ushort v = 0;
            if (co < COFF && flatk < 81) {
                int cc = flatk / 27, tap = flatk % 27;
                v = f2bf(w_off[(co * 67 + 64 + cc) * 27 + tap]);
            }
            pAc[i] = v;
        }
        for (int i = t0; i < 27 * 2 * 4 * 512; i += stride) {
            int j = i & 7, l = (i >> 3) & 63;
            int m = (i >> 9) & 3, ch = (i >> 11) & 1, k = i >> 12;
            int o = m * 16 + (l & 15);
            int c = ch * 32 + (l >> 4) * 8 + j;
            pW[i] = f2bf(w_dcn[(o * 64 + c) * 27 + k]);
        }
    }
}

// ---------------- kernel B: fused conv -> corners -> sample+GEMM ------------
// block: 16 sp; stage-2: 2 k-streams x 2 p-halves, full-line gathers,
// LDS bounce into MFMA B-frag layout (XOR-swizzled, double-buffered)
__global__ __launch_bounds__(256, 4) void k_fused(
    const ushort* __restrict__ xt, const ushort* __restrict__ pA1,
    const ushort* __restrict__ pAc, const ushort* __restrict__ pW,
    const float* __restrict__ b_off, const float* __restrict__ b_dcn,
    float* __restrict__ out)
{
    __shared__ __align__(16) char smem[33152];
    ushort* pred_lds = (ushort*)smem;            // 3456 B  bf16 [108][16]
    char*   region   = smem + 3456;              // 21504 B union:
    //   red1: f32x4[(w1*7+m)*64+lane]           (21504 B)
    //   cwi : uint4[(k*2+half)*16+p]            (13824 B)  pre-shifted byte idx
    //   cww : uint4[k*16+p] at +13824           ( 6912 B)  8 packed bf16 wgts
    //   red2: f32x4[(wv*4+m)*64+lane]           (16384 B)
    char*   Sbuf     = smem + 24960;             // 8192 B: [str][buf][16p][128B]

    const int bi   = blockIdx.x;
    const int b    = bi >> 9;
    const int sp16 = bi & 511;
    const int spg  = sp16 * 16;
    const int d    = sp16 >> 6;
    const int h    = (sp16 >> 1) & 31;
    const int w0   = (sp16 & 1) * 16;
    const int tid = threadIdx.x;
    const int wv = tid >> 6, lane = tid & 63, q = lane >> 4, r16 = lane & 15;
    const ushort* __restrict__ xb = xt + (size_t)b * DHW * 64;

    // ===== stage 1: offset conv, 57 K-chunks interleaved over 4 waves =====
    f32x4 acc1[7] = {};
    for (int c = wv; c < 57; c += 4) {
        bf16x8 bf = {};
        const ushort* pa;
        if (c < 54) {
            int tap = c >> 1, ch = c & 1;
            int dz = tap / 9, rem9 = tap - dz * 9, dy = rem9 / 3, dx = rem9 - dy * 3;
            int zz = d + dz - 1, yy = h + dy - 1, xx = w0 + r16 + dx - 1;
            bool ok = ((unsigned)zz < 8u) & ((unsigned)yy < 32u) & ((unsigned)xx < 32u);
            if (ok)
                bf = *(const bf16x8*)(xb + (size_t)((zz << 10) + (yy << 5) + xx) * 64
                                      + ch * 32 + q * 8);
            pa = pA1 + (size_t)((tap * 2 + ch) * 7) * 512 + lane * 8;
        } else {
            int t = c - 54;
            float vj[8];
            #pragma unroll
            for (int j = 0; j < 8; ++j) {
                int flatk = t * 32 + q * 8 + j;
                int cc = flatk / 27, tap = flatk % 27;
                int dz = tap / 9, rem9 = tap - dz * 9, dy = rem9 / 3, dx = rem9 - dy * 3;
                int zz = d + dz - 1, yy = h + dy - 1, xx = w0 + r16 + dx - 1;
                bool ok = (flatk < 81) & ((unsigned)zz < 8u) & ((unsigned)yy < 32u)
                          & ((unsigned)xx < 32u);
                float val = 0.f;
                if (ok)
                    val = (cc == 0) ? (-1.f + (2.f / 7.f) * (float)zz)
                        : (cc == 1) ? (-1.f + (2.f / 31.f) * (float)yy)
                                    : (-1.f + (2.f / 31.f) * (float)xx);
                vj[j] = val;
            }
            uint4 pkc;
            pkc.x = pk2bf(vj[0], vj[1]);
            pkc.y = pk2bf(vj[2], vj[3]);
            pkc.z = pk2bf(vj[4], vj[5]);
            pkc.w = pk2bf(vj[6], vj[7]);
            bf = __builtin_bit_cast(bf16x8, pkc);
            pa = pAc + (size_t)(t * 7) * 512 + lane * 8;
        }
        #pragma unroll
        for (int m = 0; m < 7; ++m)
            acc1[m] = __builtin_amdgcn_mfma_f32_16x16x32_bf16(
                *(const bf16x8*)(pa + m * 512), bf, acc1[m], 0, 0, 0);
    }
    if (wv) {
        f32x4* red1 = (f32x4*)region;
        #pragma unroll
        for (int m = 0; m < 7; ++m)
            red1[((wv - 1) * 7 + m) * 64 + lane] = acc1[m];
    }
    __syncthreads();
    if (wv == 0) {
        const f32x4* red1 = (const f32x4*)region;
        #pragma unroll
        for (int m = 0; m < 7; ++m) {
            f32x4 s = acc1[m];
            #pragma unroll
            for (int w1 = 0; w1 < 3; ++w1)
                s += red1[(w1 * 7 + m) * 64 + lane];
            #pragma unroll
            for (int r = 0; r < 4; ++r) {
                int co = m * 16 + q * 4 + r;
                if (co < COFF)
                    pred_lds[co * 16 + r16] = f2bf(s[r] + b_off[co]);
            }
        }
    }
    __syncthreads();

    // ===== corner tables =====
    uint4* cwi = (uint4*)region;
    uint4* cww = (uint4*)(region + 13824);
    for (int kp = tid; kp < 27 * 16; kp += 256) {
        int k = kp >> 4, p = kp & 15;
        float offz = bf2f(pred_lds[(k * 3 + 0) * 16 + p]);
        float offy = bf2f(pred_lds[(k * 3 + 1) * 16 + p]);
        float offx = bf2f(pred_lds[(k * 3 + 2) * 16 + p]);
        float av   = bf2f(pred_lds[(81 + k) * 16 + p]);
        float alpha = 1.f / (1.f + __expf(-av));
        int kz = k / 9, rem = k - kz * 9, ky = rem / 3, kx = rem - ky * 3;
        float pz = (float)(d + kz - 1) + offz;
        float py = (float)(h + ky - 1) + offy;
        float px = (float)(w0 + p + kx - 1) + offx;
        float fz = floorf(pz), fy = floorf(py), fx = floorf(px);
        float tz = pz - fz, ty = py - fy, tx = px - fx;
        int iz0 = (int)fz, iy0 = (int)fy, ix0 = (int)fx;
        unsigned idxs[8]; float wgts[8];
        #pragma unroll
        for (int c8 = 0; c8 < 8; ++c8) {
            int czi = c8 >> 2, cyi = (c8 >> 1) & 1, cxi = c8 & 1;
            int iz = iz0 + czi, iy = iy0 + cyi, ix = ix0 + cxi;
            float wz = czi ? tz : 1.f - tz;
            float wy = cyi ? ty : 1.f - ty;
            float wx = cxi ? tx : 1.f - tx;
            bool ok = ((unsigned)iz < 8u) && ((unsigned)iy < 32u) && ((unsigned)ix < 32u);
            idxs[c8] = ok ? ((unsigned)((iz << 10) + (iy << 5) + ix) << 7) : 0u;
            wgts[c8] = ok ? wz * wy * wx * alpha : 0.f;
        }
        cwi[(k * 2 + 0) * 16 + p] = make_uint4(idxs[0], idxs[1], idxs[2], idxs[3]);
        cwi[(k * 2 + 1) * 16 + p] = make_uint4(idxs[4], idxs[5], idxs[6], idxs[7]);
        cww[k * 16 + p] = make_uint4(pk2bf(wgts[0], wgts[1]), pk2bf(wgts[2], wgts[3]),
                                     pk2bf(wgts[4], wgts[5]), pk2bf(wgts[6], wgts[7]));
    }
    __syncthreads();

    // ===== stage 2: full-line sample + LDS bounce + GEMM =====
    // waves: str = wv>>1 (k-stream: even/odd k), ph = wv&1 (p-half & ch-half)
    // lanes: pr = lane>>3 (position in half), cg = lane&7 (8-ch group)
    const int str = wv >> 1, ph = wv & 1;
    const int pr = lane >> 3, cg = lane & 7;
    const int p2 = ph * 8 + pr;
    const char* xbB = (const char*)xb + cg * 16;
    char* Sbase = Sbuf + str * 4096;
    const unsigned swz_w = (unsigned)(p2 * 128 + ((cg * 16) ^ ((p2 & 7) << 4)));
    const unsigned swz_r = (unsigned)(r16 * 128 + ((ph * 64 + q * 16) ^ ((r16 & 7) << 4)));

    f32x4 acc2[4] = {};
    for (int t = 0; t < 14; ++t) {
        const int k = 2 * t + str;
        char* Sb = Sbase + (t & 1) * 2048;
        if (k < 27) {
            uint4 wq = cww[k * 16 + p2];
            uint4 i0 = cwi[(k * 2 + 0) * 16 + p2];
            uint4 i1 = cwi[(k * 2 + 1) * 16 + p2];
            unsigned iv[8] = {i0.x, i0.y, i0.z, i0.w, i1.x, i1.y, i1.z, i1.w};
            unsigned wp[4] = {wq.x, wq.y, wq.z, wq.w};
            float sa[8] = {};
            #pragma unroll
            for (int cp = 0; cp < 4; ++cp) {
                uint4 xa = *(const uint4*)(xbB + iv[cp * 2 + 0]);
                uint4 xc = *(const uint4*)(xbB + iv[cp * 2 + 1]);
                unsigned ua[4] = {xa.x, xa.y, xa.z, xa.w};
                unsigned ub[4] = {xc.x, xc.y, xc.z, xc.w};
                #pragma unroll
                for (int dw = 0; dw < 4; ++dw) {
                    unsigned plo = __builtin_amdgcn_perm(ub[dw], ua[dw], 0x05040100u);
                    unsigned phi = __builtin_amdgcn_perm(ub[dw], ua[dw], 0x07060302u);
                    sa[dw * 2 + 0] = dot2bf(plo, wp[cp], sa[dw * 2 + 0]);
                    sa[dw * 2 + 1] = dot2bf(phi, wp[cp], sa[dw * 2 + 1]);
                }
            }
            uint4 pk;
            pk.x = pk2bf(sa[0], sa[1]);
            pk.y = pk2bf(sa[2], sa[3]);
            pk.z = pk2bf(sa[4], sa[5]);
            pk.w = pk2bf(sa[6], sa[7]);
            *(uint4*)(Sb + swz_w) = pk;
        }
        __syncthreads();
        if (k < 27) {
            bf16x8 bfv = *(const bf16x8*)(Sb + swz_r);
            const ushort* pwk = pW + (size_t)((k * 2 + ph) * 4) * 512 + lane * 8;
            #pragma unroll
            for (int m = 0; m < 4; ++m)
                acc2[m] = __builtin_amdgcn_mfma_f32_16x16x32_bf16(
                    *(const bf16x8*)(pwk + m * 512), bfv, acc2[m], 0, 0, 0);
        }
    }

    __syncthreads();
    f32x4* red2 = (f32x4*)region;
    #pragma unroll
    for (int m = 0; m < 4; ++m)
        red2[(wv * 4 + m) * 64 + lane] = acc2[m];
    __syncthreads();
    float* __restrict__ outb = out + (size_t)b * 64 * DHW + spg;
    f32x4 s = red2[(0 * 4 + wv) * 64 + lane];
    #pragma unroll
    for (int w1 = 1; w1 < 4; ++w1)
        s += red2[(w1 * 4 + wv) * 64 + lane];
    #pragma unroll
    for (int r = 0; r < 4; ++r) {
        int o = wv * 16 + q * 4 + r;
        outb[(size_t)o * DHW + r16] = s[r] + b_dcn[o];
    }
}

extern "C" void kernel_launch(void* const* d_in, const int* in_sizes, int n_in,
                              void* d_out, int out_size, void* d_ws, size_t ws_size,
                              hipStream_t stream) {
    const float* x     = (const float*)d_in[0];
    const float* w_off = (const float*)d_in[1];
    const float* b_off = (const float*)d_in[2];
    const float* w_dcn = (const float*)d_in[3];
    const float* b_dcn = (const float*)d_in[4];
    float* out = (float*)d_out;

    ushort* xt  = (ushort*)d_ws;                          // 2,097,152 B
    ushort* pA1 = (ushort*)((char*)d_ws + 2097152);       //   387,072 B
    ushort* pAc = (ushort*)((char*)d_ws + 2484224);       //    21,504 B
    ushort* pW  = (ushort*)((char*)d_ws + 2505728);       //   221,184 B

    k_prep <<<1056, 256, 0, stream>>>(x, w_off, w_dcn, xt, pA1, pAc, pW);
    k_fused<<<1024, 256, 0, stream>>>(xt, pA1, pAc, pW, b_off, b_dcn, out);
}